// Round 16
// baseline (147.413 us; speedup 1.0000x reference)
//
#include <hip/hip_runtime.h>

typedef unsigned short u16;
typedef unsigned int   u32;
typedef __bf16 bf16x8 __attribute__((ext_vector_type(8)));
typedef float  f32x4  __attribute__((ext_vector_type(4)));

__device__ __forceinline__ u16 f2bf(float f) {
  u32 u = __float_as_uint(f);
  u += 0x7fffu + ((u >> 16) & 1u);   // RNE
  return (u16)(u >> 16);
}

__device__ __forceinline__ u32 cvt_pk_bf16(float a, float b) {
  u32 r;
  asm("v_cvt_pk_bf16_f32 %0, %1, %2" : "=v"(r) : "v"(a), "v"(b));
  return r;
}

__device__ __forceinline__ float max3f(float a, float b, float c) {
  float r;
  asm("v_max3_f32 %0, %1, %2, %3" : "=v"(r) : "v"(a), "v"(b), "v"(c));
  return r;
}

__device__ __forceinline__ void gll16(const void* g, void* l) {
  __builtin_amdgcn_global_load_lds(
      (__attribute__((address_space(1))) unsigned int*)(g),
      (__attribute__((address_space(3))) unsigned int*)(l), 16, 0, 0);
}

// bijective XCD swizzle for nwg % 8 == 0 (T1)
__device__ __forceinline__ int xcd_swz(int wg, int nwg) {
  int cpx = nwg >> 3;
  return (wg & 7) * cpx + (wg >> 3);
}

// ---------------- convert q/k/v inputs f32 -> bf16 ----------------
__device__ __forceinline__ void cvt8(const float* __restrict__ s, u16* __restrict__ d, int o) {
  float4 a = *(const float4*)(s + o);
  float4 b = *(const float4*)(s + o + 4);
  uint4 r;
  r.x = cvt_pk_bf16(a.x, a.y);
  r.y = cvt_pk_bf16(a.z, a.w);
  r.z = cvt_pk_bf16(b.x, b.y);
  r.w = cvt_pk_bf16(b.z, b.w);
  *(uint4*)(d + o) = r;
}

__global__ __launch_bounds__(256) void convert_in(
    const float* __restrict__ q, const float* __restrict__ k, const float* __restrict__ v,
    u16* __restrict__ qo, u16* __restrict__ ko, u16* __restrict__ vo) {
  int t = blockIdx.x * 256 + threadIdx.x;   // 524288 threads, 8 floats each
  int o = t * 8;
  cvt8(q, qo, o);
  cvt8(k, ko, o);
  cvt8(v, vo, o);
}

// ---------------- convert + transpose weights: Wt[n][k] = bf16(W[k][n]) ----------------
__global__ __launch_bounds__(256) void convert_w(
    const float* __restrict__ Wq, const float* __restrict__ Wk,
    const float* __restrict__ Wv, const float* __restrict__ Wo,
    u16* __restrict__ Wqt, u16* __restrict__ Wkt,
    u16* __restrict__ Wvt, u16* __restrict__ Wot) {
  __shared__ __align__(16) u16 t[64][72];
  int z = blockIdx.z;
  const float* W = (z == 0) ? Wq : (z == 1) ? Wk : (z == 2) ? Wv : Wo;
  u16* Wt = (z == 0) ? Wqt : (z == 1) ? Wkt : (z == 2) ? Wvt : Wot;
  int k0 = blockIdx.y * 64, n0 = blockIdx.x * 64;
  int tid = threadIdx.x;
#pragma unroll
  for (int e = 0; e < 4; ++e) {
    int i = e * 256 + tid;            // 0..1023
    int r = i >> 4, c4 = (i & 15) * 4;
    float4 vv = *(const float4*)(W + (size_t)(k0 + r) * 1024 + n0 + c4);
    union { u16 u[4]; uint2 w2; } p;
    p.u[0] = f2bf(vv.x); p.u[1] = f2bf(vv.y); p.u[2] = f2bf(vv.z); p.u[3] = f2bf(vv.w);
    *(uint2*)&t[r][c4] = p.w2;
  }
  __syncthreads();
#pragma unroll
  for (int e = 0; e < 2; ++e) {
    int i = e * 256 + tid;            // 0..511
    int rn = i >> 3, c8 = (i & 7) * 8;
    union { u16 u[8]; uint4 w4; } p;
#pragma unroll
    for (int kk = 0; kk < 8; ++kk) p.u[kk] = t[c8 + kk][rn];
    *(uint4*)(Wt + (size_t)(n0 + rn) * 1024 + k0 + c8) = p.w4;
  }
}

// ---------------- shared GEMM mainloop (m97 structure: 128x128 tile, BK=64) ----------------
__device__ __forceinline__ void gemm_core(
    const u16* __restrict__ A,   // [M][K] bf16
    const u16* __restrict__ Bt,  // [N][K] bf16
    int K, int m0, int n0,
    u16* As, u16* Bs, f32x4 acc[4][4]) {
  const int tid = threadIdx.x;
  const int l = tid & 63;
  const int g = l >> 4, q16 = l & 15;
  const int wv = tid >> 6;
  const int wr = wv >> 1, wc = wv & 1;
#pragma unroll
  for (int mi = 0; mi < 4; ++mi)
#pragma unroll
    for (int ni = 0; ni < 4; ++ni) acc[mi][ni] = (f32x4){0.f, 0.f, 0.f, 0.f};

  for (int k0 = 0; k0 < K; k0 += 64) {
    __syncthreads();
#pragma unroll
    for (int c = 0; c < 4; ++c) {
      int i = c * 256 + tid;          // 0..1023 16B slots
      int row = i >> 3, ce = (i & 7) * 8;
      gll16(A + (size_t)(m0 + row) * K + k0 + ce, As + i * 8);
      gll16(Bt + (size_t)(n0 + row) * K + k0 + ce, Bs + i * 8);
    }
    __syncthreads();
#pragma unroll
    for (int kb = 0; kb < 2; ++kb) {
      bf16x8 af[4], bfr[4];
#pragma unroll
      for (int mi = 0; mi < 4; ++mi)
        af[mi] = *(const bf16x8*)(As + (wr * 64 + mi * 16 + q16) * 64 + kb * 32 + g * 8);
#pragma unroll
      for (int ni = 0; ni < 4; ++ni)
        bfr[ni] = *(const bf16x8*)(Bs + (wc * 64 + ni * 16 + q16) * 64 + kb * 32 + g * 8);
#pragma unroll
      for (int mi = 0; mi < 4; ++mi)
#pragma unroll
        for (int ni = 0; ni < 4; ++ni)
          acc[mi][ni] = __builtin_amdgcn_mfma_f32_16x16x32_bf16(af[mi], bfr[ni], acc[mi][ni], 0, 0, 0);
    }
  }
}

// ---------------- fused QKV projection ----------------
// q/k slices -> split-head bf16 [BH][S][64]; v slice -> V^T [BH][64][S] DIRECTLY
__global__ __launch_bounds__(256) void gemm_qkv(
    const u16* __restrict__ qA, const u16* __restrict__ kA, const u16* __restrict__ vA,
    const u16* __restrict__ qW, const u16* __restrict__ kW, const u16* __restrict__ vW,
    const float* __restrict__ qb, const float* __restrict__ kb2, const float* __restrict__ vb,
    u16* __restrict__ Qh, u16* __restrict__ Kh, u16* __restrict__ Vtb, float qscale) {
  __shared__ __align__(16) u16 As[128 * 64];
  __shared__ __align__(16) u16 Bs[128 * 64];
  int z = blockIdx.z;
  const u16* A   = (z == 0) ? qA : (z == 1) ? kA : vA;
  const u16* Bt  = (z == 0) ? qW : (z == 1) ? kW : vW;
  const float* bias = (z == 0) ? qb : (z == 1) ? kb2 : vb;
  float scale = (z == 0) ? qscale : 1.0f;
  int swz = xcd_swz(blockIdx.y * gridDim.x + blockIdx.x, gridDim.x * gridDim.y);
  int m0 = (swz >> 3) * 128, n0 = (swz & 7) * 128;
  f32x4 acc[4][4];
  gemm_core(A, Bt, 1024, m0, n0, As, Bs, acc);

  const int tid = threadIdx.x;
  const int l = tid & 63;
  const int g = l >> 4, q16 = l & 15;
  const int wv = tid >> 6;
  const int wr = wv >> 1, wc = wv & 1;

  if (z == 2) {
    // V^T epilogue: row = bh*64 + dk, col = s; pack 4 j (consecutive s) into 8B
#pragma unroll
    for (int ni = 0; ni < 4; ++ni) {
      int n = n0 + wc * 64 + ni * 16 + q16;
      float bvv = bias[n];
      int hh = n >> 6, dk = n & 63;
#pragma unroll
      for (int mi = 0; mi < 4; ++mi) {
        int m = m0 + wr * 64 + mi * 16 + g * 4;   // j=0; all 4 j share b
        int b = m >> 11, s = m & 2047;
        uint2 w;
        w.x = cvt_pk_bf16(acc[mi][ni][0] + bvv, acc[mi][ni][1] + bvv);
        w.y = cvt_pk_bf16(acc[mi][ni][2] + bvv, acc[mi][ni][3] + bvv);
        *(uint2*)&Vtb[(((size_t)b * 16 + hh) * 64 + dk) * 2048 + s] = w;
      }
    }
  } else {
    u16* out = (z == 0) ? Qh : Kh;
#pragma unroll
    for (int ni = 0; ni < 4; ++ni) {
      int n = n0 + wc * 64 + ni * 16 + q16;
      float bvv = bias[n];
      int hh = n >> 6, dk = n & 63;
#pragma unroll
      for (int mi = 0; mi < 4; ++mi) {
#pragma unroll
        for (int j = 0; j < 4; ++j) {
          int m = m0 + wr * 64 + mi * 16 + g * 4 + j;
          int b = m >> 11, s = m & 2047;
          float v = (acc[mi][ni][j] + bvv) * scale;
          out[(((size_t)b * 16 + hh) * 2048 + s) * 64 + dk] = f2bf(v);
        }
      }
    }
  }
}

// ---------------- output projection: f32 out + bias ----------------
__global__ __launch_bounds__(256) void gemm_out(
    const u16* __restrict__ A, const u16* __restrict__ Bt,
    const float* __restrict__ bias, float* __restrict__ Out) {
  __shared__ __align__(16) u16 As[128 * 64];
  __shared__ __align__(16) u16 Bs[128 * 64];
  int swz = xcd_swz(blockIdx.y * gridDim.x + blockIdx.x, gridDim.x * gridDim.y);
  int m0 = (swz >> 3) * 128, n0 = (swz & 7) * 128;
  f32x4 acc[4][4];
  gemm_core(A, Bt, 1024, m0, n0, As, Bs, acc);

  const int tid = threadIdx.x;
  const int l = tid & 63;
  const int g = l >> 4, q16 = l & 15;
  const int wv = tid >> 6;
  const int wr = wv >> 1, wc = wv & 1;
#pragma unroll
  for (int ni = 0; ni < 4; ++ni) {
    int n = n0 + wc * 64 + ni * 16 + q16;
    float bvv = bias[n];
#pragma unroll
    for (int mi = 0; mi < 4; ++mi) {
#pragma unroll
      for (int j = 0; j < 4; ++j) {
        int m = m0 + wr * 64 + mi * 16 + g * 4 + j;
        Out[(size_t)m * 1024 + n] = acc[mi][ni][j] + bvv;
      }
    }
  }
}

// ---------------- flash attention (R6/R13 structure: 4 waves x 32 q, tri-buffer) ----------------
// Zero per-tile cross-lane ops in the common path: vote-based defer-max + deferred row-sum;
// in-register P (cvt_pk + permlane, proven R4); 0-conflict XOR-swizzled K/V LDS;
// tri-buffer + counted vmcnt(4); XCD swizzle.
__global__ __launch_bounds__(256, 3) void attn_kernel(
    const u16* __restrict__ Qh,   // [32][2048][64]
    const u16* __restrict__ Kh,   // [32][2048][64]
    const u16* __restrict__ Vt,   // [32][64][2048]
    u16* __restrict__ Xb) {       // [4096][1024]
  __shared__ __align__(16) u16 Ks[3][64 * 64];
  __shared__ __align__(16) u16 Vs[3][64 * 64];

  const int tid = threadIdx.x;
  const int l = tid & 63, wv = tid >> 6;
  const int g = l >> 4, q16 = l & 15;
  const int swz = xcd_swz(blockIdx.y * gridDim.x + blockIdx.x, gridDim.x * gridDim.y);
  const int qblk = swz & 15, bh = swz >> 4;
  const int b = bh >> 4, h = bh & 15;
  const int qrow0 = qblk * 128 + wv * 32;

  const u16* Kbase = Kh + (size_t)bh * 2048 * 64;
  const u16* Vbase = Vt + (size_t)bh * 64 * 2048;

  bf16x8 bq[2][2];
#pragma unroll
  for (int nq = 0; nq < 2; ++nq)
#pragma unroll
    for (int kb = 0; kb < 2; ++kb)
      bq[nq][kb] = *(const bf16x8*)(Qh + ((size_t)bh * 2048 + qrow0 + nq * 16 + q16) * 64 +
                                    kb * 32 + g * 8);

  f32x4 x[2][4];
#pragma unroll
  for (int nq = 0; nq < 2; ++nq)
#pragma unroll
    for (int ni = 0; ni < 4; ++ni) x[nq][ni] = (f32x4){0.f, 0.f, 0.f, 0.f};
  float m_run[2] = {-3e38f, -3e38f};
  float l_run[2] = {0.f, 0.f};     // PER-LANE partial sums (own 16 k-slices)

#define STAGE(t, bb)                                                            \
  {                                                                             \
    _Pragma("unroll")                                                           \
    for (int c = 0; c < 2; ++c) {                                               \
      int i = c * 256 + tid;                                                    \
      int row = i >> 3, sc8 = (i & 7) ^ (row & 7);                              \
      gll16(Kbase + ((size_t)(t) * 64 + row) * 64 + sc8 * 8, &Ks[bb][i * 8]);   \
      gll16(Vbase + (size_t)row * 2048 + (t) * 64 + sc8 * 8, &Vs[bb][i * 8]);   \
    }                                                                           \
  }

  STAGE(0, 0);
  STAGE(1, 1);
  asm volatile("s_waitcnt vmcnt(4)" ::: "memory");
  __builtin_amdgcn_s_barrier();

  for (int kt = 0; kt < 32; ++kt) {
    const int cb = kt % 3;
    if (kt + 2 < 32) STAGE(kt + 2, (kt + 2) % 3);

    // QK^T swapped: st[mi][nq] = S^T fragment (lane: q = nq*16 + l&15; k = mi*16 + g*4 + j)
    f32x4 st[4][2];
#pragma unroll
    for (int mi = 0; mi < 4; ++mi)
#pragma unroll
      for (int nq = 0; nq < 2; ++nq) st[mi][nq] = (f32x4){0.f, 0.f, 0.f, 0.f};
#pragma unroll
    for (int mi = 0; mi < 4; ++mi) {
      int row = mi * 16 + q16;
#pragma unroll
      for (int kb = 0; kb < 2; ++kb) {
        int pc8 = (kb * 4 + g) ^ (row & 7);
        bf16x8 ak = *(const bf16x8*)(&Ks[cb][row * 64 + pc8 * 8]);
#pragma unroll
        for (int nq = 0; nq < 2; ++nq)
          st[mi][nq] = __builtin_amdgcn_mfma_f32_16x16x32_bf16(ak, bq[nq][kb], st[mi][nq], 0, 0, 0);
      }
    }

    // V tile ds_reads issued now; latency hides under softmax VALU below
    bf16x8 vf[2][4];
#pragma unroll
    for (int kkb = 0; kkb < 2; ++kkb)
#pragma unroll
      for (int ni = 0; ni < 4; ++ni) {
        int d = ni * 16 + q16;
        int pc8 = (kkb * 4 + g) ^ (d & 7);
        vf[kkb][ni] = *(const bf16x8*)(&Vs[cb][d * 64 + pc8 * 8]);
      }

    // softmax, zero cross-lane in the common path
    bf16x8 ap[2][2];
#pragma unroll
    for (int nq = 0; nq < 2; ++nq) {
      // in-lane partial max of own 16 scores (max3 tree)
      float ma = max3f(st[0][nq][0], st[0][nq][1], st[0][nq][2]);
      ma = max3f(ma, st[0][nq][3], st[1][nq][0]);
      ma = max3f(ma, st[1][nq][1], st[1][nq][2]);
      ma = fmaxf(ma, st[1][nq][3]);
      float mb = max3f(st[2][nq][0], st[2][nq][1], st[2][nq][2]);
      mb = max3f(mb, st[2][nq][3], st[3][nq][0]);
      mb = max3f(mb, st[3][nq][1], st[3][nq][2]);
      mb = fmaxf(mb, st[3][nq][3]);
      float mx = fmaxf(ma, mb);

      float mref, sf;
      if (__all(mx <= m_run[nq] + 8.f)) {
        // every lane's own scores bounded by m_run+8 -> P <= 2^8; no shfl, no rescale
        mref = m_run[nq]; sf = 1.f;
      } else {
        // rare: full row reduce + rescale
        float mrow = fmaxf(mx, __shfl_xor(mx, 16));
        mrow = fmaxf(mrow, __shfl_xor(mrow, 32));
        mref = fmaxf(m_run[nq], mrow);
        sf = __builtin_amdgcn_exp2f(m_run[nq] - mref);
        m_run[nq] = mref;
#pragma unroll
        for (int j = 0; j < 4; ++j) {
          float sfx = __shfl(sf, g * 4 + j);  // sf of q-row g*4+j lives in lane g*4+j
#pragma unroll
          for (int ni = 0; ni < 4; ++ni) x[nq][ni][j] *= sfx;
        }
      }

      float rs = 0.f;
#pragma unroll
      for (int mi = 0; mi < 4; ++mi)
#pragma unroll
        for (int j = 0; j < 4; ++j) {
          float p = __builtin_amdgcn_exp2f(st[mi][nq][j] - mref);
          st[mi][nq][j] = p;
          rs += p;
        }
      l_run[nq] = l_run[nq] * sf + rs;   // per-lane partial; cross-g reduce deferred to end

      // P -> PV A-fragments in-register (T12; composition proven in R4)
#pragma unroll
      for (int kkb = 0; kkb < 2; ++kkb) {
        u32 a0 = cvt_pk_bf16(st[kkb * 2][nq][0],     st[kkb * 2][nq][1]);
        u32 a1 = cvt_pk_bf16(st[kkb * 2][nq][2],     st[kkb * 2][nq][3]);
        u32 b0 = cvt_pk_bf16(st[kkb * 2 + 1][nq][0], st[kkb * 2 + 1][nq][1]);
        u32 b1 = cvt_pk_bf16(st[kkb * 2 + 1][nq][2], st[kkb * 2 + 1][nq][3]);
        asm("v_permlane32_swap_b32 %0, %1" : "+v"(a0), "+v"(b0));
        asm("v_permlane16_swap_b32 %0, %1" : "+v"(a0), "+v"(b0));
        asm("v_permlane32_swap_b32 %0, %1" : "+v"(a1), "+v"(b1));
        asm("v_permlane16_swap_b32 %0, %1" : "+v"(a1), "+v"(b1));
        union { u32 u[4]; bf16x8 v; } pk_;
        pk_.u[0] = a0; pk_.u[1] = a1; pk_.u[2] = b0; pk_.u[3] = b1;
        ap[nq][kkb] = pk_.v;
      }
    }

    // PV: X(32q x 64d) += P(32x64) @ V^T-tile (vf registers, shared across nq)
#pragma unroll
    for (int kkb = 0; kkb < 2; ++kkb)
#pragma unroll
      for (int ni = 0; ni < 4; ++ni)
#pragma unroll
        for (int nq = 0; nq < 2; ++nq)
          x[nq][ni] = __builtin_amdgcn_mfma_f32_16x16x32_bf16(ap[nq][kkb], vf[kkb][ni],
                                                              x[nq][ni], 0, 0, 0);

    // counted wait: tile kt+1's 4 loads landed; kt+2's 4 stay in flight across barrier
    if (kt < 30) {
      asm volatile("s_waitcnt vmcnt(4)" ::: "memory");
      __builtin_amdgcn_s_barrier();
    } else if (kt == 30) {
      asm volatile("s_waitcnt vmcnt(0)" ::: "memory");
      __builtin_amdgcn_s_barrier();
    }
  }

  // finalize: one-time cross-g row-sum reduce, divide, write merged-head bf16
#pragma unroll
  for (int nq = 0; nq < 2; ++nq) {
    float lt = l_run[nq] + __shfl_xor(l_run[nq], 16);
    lt += __shfl_xor(lt, 32);
    float li = 1.0f / lt;
#pragma unroll
    for (int j = 0; j < 4; ++j) {
      float lv = __shfl(li, g * 4 + j);
      int srw = b * 2048 + qblk * 128 + wv * 32 + nq * 16 + g * 4 + j;
#pragma unroll
      for (int ni = 0; ni < 4; ++ni) {
        int col = h * 64 + ni * 16 + q16;
        Xb[(size_t)srw * 1024 + col] = f2bf(x[nq][ni][j] * lv);
      }
    }
  }
#undef STAGE
}

// ---------------- host launch ----------------
extern "C" void kernel_launch(void* const* d_in, const int* in_sizes, int n_in,
                              void* d_out, int out_size, void* d_ws, size_t ws_size,
                              hipStream_t stream) {
  (void)in_sizes; (void)n_in; (void)out_size; (void)ws_size;
  const float* q  = (const float*)d_in[0];
  const float* k  = (const float*)d_in[1];
  const float* v  = (const float*)d_in[2];
  const float* Wq = (const float*)d_in[3];
  const float* bq = (const float*)d_in[4];
  const float* Wk = (const float*)d_in[5];
  const float* bk = (const float*)d_in[6];
  const float* Wv = (const float*)d_in[7];
  const float* bv = (const float*)d_in[8];
  const float* Wo = (const float*)d_in[9];
  const float* bo = (const float*)d_in[10];

  char* W = (char*)d_ws;
  const size_t MB = 1ull << 20;
  u16* qbf = (u16*)(W + 0 * MB);    // [4096][1024] bf16
  u16* kbf = (u16*)(W + 8 * MB);
  u16* vbf = (u16*)(W + 16 * MB);
  u16* wqt = (u16*)(W + 24 * MB);   // [1024][1024] bf16 (transposed)
  u16* wkt = (u16*)(W + 26 * MB);
  u16* wvt = (u16*)(W + 28 * MB);
  u16* wot = (u16*)(W + 30 * MB);
  u16* Qh  = (u16*)(W + 32 * MB);   // [32][2048][64] bf16 (pre-scaled)
  u16* Kh  = (u16*)(W + 40 * MB);
  u16* Vtb = (u16*)(W + 56 * MB);   // [32][64][2048] (written directly by gemm_qkv)
  u16* Xb  = (u16*)(W + 64 * MB);   // [4096][1024] bf16

  convert_in<<<2048, 256, 0, stream>>>(q, k, v, qbf, kbf, vbf);
  convert_w<<<dim3(16, 16, 4), 256, 0, stream>>>(Wq, Wk, Wv, Wo, wqt, wkt, wvt, wot);
  const float QSCALE = 0.125f * 1.4426950408889634f;  // fold 1/sqrt(dk) * log2(e) into Q
  gemm_qkv<<<dim3(8, 32, 3), 256, 0, stream>>>(qbf, kbf, vbf, wqt, wkt, wvt,
                                               bq, bk, bv, Qh, Kh, Vtb, QSCALE);
  attn_kernel<<<dim3(16, 32), 256, 0, stream>>>(Qh, Kh, Vtb, Xb);
  gemm_out<<<dim3(8, 32), 256, 0, stream>>>(Xb, wot, bo, (float*)d_out);
}

// Round 18
// 147.098 us; speedup vs baseline: 1.0021x; 1.0021x over previous
//
#include <hip/hip_runtime.h>

typedef unsigned short u16;
typedef unsigned int   u32;
typedef __bf16 bf16x8 __attribute__((ext_vector_type(8)));
typedef float  f32x4  __attribute__((ext_vector_type(4)));

__device__ __forceinline__ u16 f2bf(float f) {
  u32 u = __float_as_uint(f);
  u += 0x7fffu + ((u >> 16) & 1u);   // RNE
  return (u16)(u >> 16);
}

__device__ __forceinline__ u32 cvt_pk_bf16(float a, float b) {
  u32 r;
  asm("v_cvt_pk_bf16_f32 %0, %1, %2" : "=v"(r) : "v"(a), "v"(b));
  return r;
}

__device__ __forceinline__ float max3f(float a, float b, float c) {
  float r;
  asm("v_max3_f32 %0, %1, %2, %3" : "=v"(r) : "v"(a), "v"(b), "v"(c));
  return r;
}

__device__ __forceinline__ void gll16(const void* g, void* l) {
  __builtin_amdgcn_global_load_lds(
      (__attribute__((address_space(1))) unsigned int*)(g),
      (__attribute__((address_space(3))) unsigned int*)(l), 16, 0, 0);
}

// bijective XCD swizzle for nwg % 8 == 0 (T1)
__device__ __forceinline__ int xcd_swz(int wg, int nwg) {
  int cpx = nwg >> 3;
  return (wg & 7) * cpx + (wg >> 3);
}

// ---------------- convert q/k/v inputs f32 -> bf16 ----------------
__device__ __forceinline__ void cvt8(const float* __restrict__ s, u16* __restrict__ d, int o) {
  float4 a = *(const float4*)(s + o);
  float4 b = *(const float4*)(s + o + 4);
  uint4 r;
  r.x = cvt_pk_bf16(a.x, a.y);
  r.y = cvt_pk_bf16(a.z, a.w);
  r.z = cvt_pk_bf16(b.x, b.y);
  r.w = cvt_pk_bf16(b.z, b.w);
  *(uint4*)(d + o) = r;
}

__global__ __launch_bounds__(256) void convert_in(
    const float* __restrict__ q, const float* __restrict__ k, const float* __restrict__ v,
    u16* __restrict__ qo, u16* __restrict__ ko, u16* __restrict__ vo) {
  int t = blockIdx.x * 256 + threadIdx.x;   // 524288 threads, 8 floats each
  int o = t * 8;
  cvt8(q, qo, o);
  cvt8(k, ko, o);
  cvt8(v, vo, o);
}

// ---------------- convert + transpose weights: Wt[n][k] = bf16(W[k][n]) ----------------
__global__ __launch_bounds__(256) void convert_w(
    const float* __restrict__ Wq, const float* __restrict__ Wk,
    const float* __restrict__ Wv, const float* __restrict__ Wo,
    u16* __restrict__ Wqt, u16* __restrict__ Wkt,
    u16* __restrict__ Wvt, u16* __restrict__ Wot) {
  __shared__ __align__(16) u16 t[64][72];
  int z = blockIdx.z;
  const float* W = (z == 0) ? Wq : (z == 1) ? Wk : (z == 2) ? Wv : Wo;
  u16* Wt = (z == 0) ? Wqt : (z == 1) ? Wkt : (z == 2) ? Wvt : Wot;
  int k0 = blockIdx.y * 64, n0 = blockIdx.x * 64;
  int tid = threadIdx.x;
#pragma unroll
  for (int e = 0; e < 4; ++e) {
    int i = e * 256 + tid;            // 0..1023
    int r = i >> 4, c4 = (i & 15) * 4;
    float4 vv = *(const float4*)(W + (size_t)(k0 + r) * 1024 + n0 + c4);
    union { u16 u[4]; uint2 w2; } p;
    p.u[0] = f2bf(vv.x); p.u[1] = f2bf(vv.y); p.u[2] = f2bf(vv.z); p.u[3] = f2bf(vv.w);
    *(uint2*)&t[r][c4] = p.w2;
  }
  __syncthreads();
#pragma unroll
  for (int e = 0; e < 2; ++e) {
    int i = e * 256 + tid;            // 0..511
    int rn = i >> 3, c8 = (i & 7) * 8;
    union { u16 u[8]; uint4 w4; } p;
#pragma unroll
    for (int kk = 0; kk < 8; ++kk) p.u[kk] = t[c8 + kk][rn];
    *(uint4*)(Wt + (size_t)(n0 + rn) * 1024 + k0 + c8) = p.w4;
  }
}

// ---------------- shared GEMM mainloop (m97 structure: 128x128 tile, BK=64) ----------------
__device__ __forceinline__ void gemm_core(
    const u16* __restrict__ A,   // [M][K] bf16
    const u16* __restrict__ Bt,  // [N][K] bf16
    int K, int m0, int n0,
    u16* As, u16* Bs, f32x4 acc[4][4]) {
  const int tid = threadIdx.x;
  const int l = tid & 63;
  const int g = l >> 4, q16 = l & 15;
  const int wv = tid >> 6;
  const int wr = wv >> 1, wc = wv & 1;
#pragma unroll
  for (int mi = 0; mi < 4; ++mi)
#pragma unroll
    for (int ni = 0; ni < 4; ++ni) acc[mi][ni] = (f32x4){0.f, 0.f, 0.f, 0.f};

  for (int k0 = 0; k0 < K; k0 += 64) {
    __syncthreads();
#pragma unroll
    for (int c = 0; c < 4; ++c) {
      int i = c * 256 + tid;          // 0..1023 16B slots
      int row = i >> 3, ce = (i & 7) * 8;
      gll16(A + (size_t)(m0 + row) * K + k0 + ce, As + i * 8);
      gll16(Bt + (size_t)(n0 + row) * K + k0 + ce, Bs + i * 8);
    }
    __syncthreads();
#pragma unroll
    for (int kb = 0; kb < 2; ++kb) {
      bf16x8 af[4], bfr[4];
#pragma unroll
      for (int mi = 0; mi < 4; ++mi)
        af[mi] = *(const bf16x8*)(As + (wr * 64 + mi * 16 + q16) * 64 + kb * 32 + g * 8);
#pragma unroll
      for (int ni = 0; ni < 4; ++ni)
        bfr[ni] = *(const bf16x8*)(Bs + (wc * 64 + ni * 16 + q16) * 64 + kb * 32 + g * 8);
#pragma unroll
      for (int mi = 0; mi < 4; ++mi)
#pragma unroll
        for (int ni = 0; ni < 4; ++ni)
          acc[mi][ni] = __builtin_amdgcn_mfma_f32_16x16x32_bf16(af[mi], bfr[ni], acc[mi][ni], 0, 0, 0);
    }
  }
}

// ---------------- fused QKV projection ----------------
// q/k slices -> split-head bf16 [BH][S][64]; v slice -> V^T [BH][64][S] DIRECTLY
__global__ __launch_bounds__(256) void gemm_qkv(
    const u16* __restrict__ qA, const u16* __restrict__ kA, const u16* __restrict__ vA,
    const u16* __restrict__ qW, const u16* __restrict__ kW, const u16* __restrict__ vW,
    const float* __restrict__ qb, const float* __restrict__ kb2, const float* __restrict__ vb,
    u16* __restrict__ Qh, u16* __restrict__ Kh, u16* __restrict__ Vtb, float qscale) {
  __shared__ __align__(16) u16 As[128 * 64];
  __shared__ __align__(16) u16 Bs[128 * 64];
  int z = blockIdx.z;
  const u16* A   = (z == 0) ? qA : (z == 1) ? kA : vA;
  const u16* Bt  = (z == 0) ? qW : (z == 1) ? kW : vW;
  const float* bias = (z == 0) ? qb : (z == 1) ? kb2 : vb;
  float scale = (z == 0) ? qscale : 1.0f;
  int swz = xcd_swz(blockIdx.y * gridDim.x + blockIdx.x, gridDim.x * gridDim.y);
  int m0 = (swz >> 3) * 128, n0 = (swz & 7) * 128;
  f32x4 acc[4][4];
  gemm_core(A, Bt, 1024, m0, n0, As, Bs, acc);

  const int tid = threadIdx.x;
  const int l = tid & 63;
  const int g = l >> 4, q16 = l & 15;
  const int wv = tid >> 6;
  const int wr = wv >> 1, wc = wv & 1;

  if (z == 2) {
    // V^T epilogue: row = bh*64 + dk, col = s; pack 4 j (consecutive s) into 8B
#pragma unroll
    for (int ni = 0; ni < 4; ++ni) {
      int n = n0 + wc * 64 + ni * 16 + q16;
      float bvv = bias[n];
      int hh = n >> 6, dk = n & 63;
#pragma unroll
      for (int mi = 0; mi < 4; ++mi) {
        int m = m0 + wr * 64 + mi * 16 + g * 4;   // j=0; all 4 j share b
        int b = m >> 11, s = m & 2047;
        uint2 w;
        w.x = cvt_pk_bf16(acc[mi][ni][0] + bvv, acc[mi][ni][1] + bvv);
        w.y = cvt_pk_bf16(acc[mi][ni][2] + bvv, acc[mi][ni][3] + bvv);
        *(uint2*)&Vtb[(((size_t)b * 16 + hh) * 64 + dk) * 2048 + s] = w;
      }
    }
  } else {
    u16* out = (z == 0) ? Qh : Kh;
#pragma unroll
    for (int ni = 0; ni < 4; ++ni) {
      int n = n0 + wc * 64 + ni * 16 + q16;
      float bvv = bias[n];
      int hh = n >> 6, dk = n & 63;
#pragma unroll
      for (int mi = 0; mi < 4; ++mi) {
#pragma unroll
        for (int j = 0; j < 4; ++j) {
          int m = m0 + wr * 64 + mi * 16 + g * 4 + j;
          int b = m >> 11, s = m & 2047;
          float v = (acc[mi][ni][j] + bvv) * scale;
          out[(((size_t)b * 16 + hh) * 2048 + s) * 64 + dk] = f2bf(v);
        }
      }
    }
  }
}

// ---------------- output projection: f32 out + bias ----------------
__global__ __launch_bounds__(256) void gemm_out(
    const u16* __restrict__ A, const u16* __restrict__ Bt,
    const float* __restrict__ bias, float* __restrict__ Out) {
  __shared__ __align__(16) u16 As[128 * 64];
  __shared__ __align__(16) u16 Bs[128 * 64];
  int swz = xcd_swz(blockIdx.y * gridDim.x + blockIdx.x, gridDim.x * gridDim.y);
  int m0 = (swz >> 3) * 128, n0 = (swz & 7) * 128;
  f32x4 acc[4][4];
  gemm_core(A, Bt, 1024, m0, n0, As, Bs, acc);

  const int tid = threadIdx.x;
  const int l = tid & 63;
  const int g = l >> 4, q16 = l & 15;
  const int wv = tid >> 6;
  const int wr = wv >> 1, wc = wv & 1;
#pragma unroll
  for (int ni = 0; ni < 4; ++ni) {
    int n = n0 + wc * 64 + ni * 16 + q16;
    float bvv = bias[n];
#pragma unroll
    for (int mi = 0; mi < 4; ++mi) {
#pragma unroll
      for (int j = 0; j < 4; ++j) {
        int m = m0 + wr * 64 + mi * 16 + g * 4 + j;
        Out[(size_t)m * 1024 + n] = acc[mi][ni][j] + bvv;
      }
    }
  }
}

// ---------------- flash attention (R6/R13 structure: 4 waves x 32 q, tri-buffer) ----------------
// Zero per-tile cross-lane ops in the common path: vote-based defer-max + deferred row-sum;
// in-register P (cvt_pk + permlane, proven R4); 0-conflict XOR-swizzled K/V LDS;
// tri-buffer + counted vmcnt(4); XCD swizzle.
__global__ __launch_bounds__(256, 3) void attn_kernel(
    const u16* __restrict__ Qh,   // [32][2048][64]
    const u16* __restrict__ Kh,   // [32][2048][64]
    const u16* __restrict__ Vt,   // [32][64][2048]
    u16* __restrict__ Xb) {       // [4096][1024]
  __shared__ __align__(16) u16 Ks[3][64 * 64];
  __shared__ __align__(16) u16 Vs[3][64 * 64];

  const int tid = threadIdx.x;
  const int l = tid & 63, wv = tid >> 6;
  const int g = l >> 4, q16 = l & 15;
  const int swz = xcd_swz(blockIdx.y * gridDim.x + blockIdx.x, gridDim.x * gridDim.y);
  const int qblk = swz & 15, bh = swz >> 4;
  const int b = bh >> 4, h = bh & 15;
  const int qrow0 = qblk * 128 + wv * 32;

  const u16* Kbase = Kh + (size_t)bh * 2048 * 64;
  const u16* Vbase = Vt + (size_t)bh * 64 * 2048;

  bf16x8 bq[2][2];
#pragma unroll
  for (int nq = 0; nq < 2; ++nq)
#pragma unroll
    for (int kb = 0; kb < 2; ++kb)
      bq[nq][kb] = *(const bf16x8*)(Qh + ((size_t)bh * 2048 + qrow0 + nq * 16 + q16) * 64 +
                                    kb * 32 + g * 8);

  f32x4 x[2][4];
#pragma unroll
  for (int nq = 0; nq < 2; ++nq)
#pragma unroll
    for (int ni = 0; ni < 4; ++ni) x[nq][ni] = (f32x4){0.f, 0.f, 0.f, 0.f};
  float m_run[2] = {-3e38f, -3e38f};
  float l_run[2] = {0.f, 0.f};     // PER-LANE partial sums (own 16 k-slices)

#define STAGE(t, bb)                                                            \
  {                                                                             \
    _Pragma("unroll")                                                           \
    for (int c = 0; c < 2; ++c) {                                               \
      int i = c * 256 + tid;                                                    \
      int row = i >> 3, sc8 = (i & 7) ^ (row & 7);                              \
      gll16(Kbase + ((size_t)(t) * 64 + row) * 64 + sc8 * 8, &Ks[bb][i * 8]);   \
      gll16(Vbase + (size_t)row * 2048 + (t) * 64 + sc8 * 8, &Vs[bb][i * 8]);   \
    }                                                                           \
  }

  STAGE(0, 0);
  STAGE(1, 1);
  asm volatile("s_waitcnt vmcnt(4)" ::: "memory");
  __builtin_amdgcn_s_barrier();

  for (int kt = 0; kt < 32; ++kt) {
    const int cb = kt % 3;
    if (kt + 2 < 32) STAGE(kt + 2, (kt + 2) % 3);

    // QK^T swapped: st[mi][nq] = S^T fragment (lane: q = nq*16 + l&15; k = mi*16 + g*4 + j)
    f32x4 st[4][2];
#pragma unroll
    for (int mi = 0; mi < 4; ++mi)
#pragma unroll
      for (int nq = 0; nq < 2; ++nq) st[mi][nq] = (f32x4){0.f, 0.f, 0.f, 0.f};
#pragma unroll
    for (int mi = 0; mi < 4; ++mi) {
      int row = mi * 16 + q16;
#pragma unroll
      for (int kb = 0; kb < 2; ++kb) {
        int pc8 = (kb * 4 + g) ^ (row & 7);
        bf16x8 ak = *(const bf16x8*)(&Ks[cb][row * 64 + pc8 * 8]);
#pragma unroll
        for (int nq = 0; nq < 2; ++nq)
          st[mi][nq] = __builtin_amdgcn_mfma_f32_16x16x32_bf16(ak, bq[nq][kb], st[mi][nq], 0, 0, 0);
      }
    }

    // V tile ds_reads issued now; latency hides under softmax VALU below
    bf16x8 vf[2][4];
#pragma unroll
    for (int kkb = 0; kkb < 2; ++kkb)
#pragma unroll
      for (int ni = 0; ni < 4; ++ni) {
        int d = ni * 16 + q16;
        int pc8 = (kkb * 4 + g) ^ (d & 7);
        vf[kkb][ni] = *(const bf16x8*)(&Vs[cb][d * 64 + pc8 * 8]);
      }

    // softmax, zero cross-lane in the common path
    bf16x8 ap[2][2];
#pragma unroll
    for (int nq = 0; nq < 2; ++nq) {
      // in-lane partial max of own 16 scores (max3 tree)
      float ma = max3f(st[0][nq][0], st[0][nq][1], st[0][nq][2]);
      ma = max3f(ma, st[0][nq][3], st[1][nq][0]);
      ma = max3f(ma, st[1][nq][1], st[1][nq][2]);
      ma = fmaxf(ma, st[1][nq][3]);
      float mb = max3f(st[2][nq][0], st[2][nq][1], st[2][nq][2]);
      mb = max3f(mb, st[2][nq][3], st[3][nq][0]);
      mb = max3f(mb, st[3][nq][1], st[3][nq][2]);
      mb = fmaxf(mb, st[3][nq][3]);
      float mx = fmaxf(ma, mb);

      float mref, sf;
      if (__all(mx <= m_run[nq] + 8.f)) {
        // every lane's own scores bounded by m_run+8 -> P <= 2^8; no shfl, no rescale
        mref = m_run[nq]; sf = 1.f;
      } else {
        // rare: full row reduce + rescale
        float mrow = fmaxf(mx, __shfl_xor(mx, 16));
        mrow = fmaxf(mrow, __shfl_xor(mrow, 32));
        mref = fmaxf(m_run[nq], mrow);
        sf = __builtin_amdgcn_exp2f(m_run[nq] - mref);
        m_run[nq] = mref;
#pragma unroll
        for (int j = 0; j < 4; ++j) {
          float sfx = __shfl(sf, g * 4 + j);  // sf of q-row g*4+j lives in lane g*4+j
#pragma unroll
          for (int ni = 0; ni < 4; ++ni) x[nq][ni][j] *= sfx;
        }
      }

      float rs = 0.f;
#pragma unroll
      for (int mi = 0; mi < 4; ++mi)
#pragma unroll
        for (int j = 0; j < 4; ++j) {
          float p = __builtin_amdgcn_exp2f(st[mi][nq][j] - mref);
          st[mi][nq][j] = p;
          rs += p;
        }
      l_run[nq] = l_run[nq] * sf + rs;   // per-lane partial; cross-g reduce deferred to end

      // P -> PV A-fragments in-register (T12; composition proven in R4)
#pragma unroll
      for (int kkb = 0; kkb < 2; ++kkb) {
        u32 a0 = cvt_pk_bf16(st[kkb * 2][nq][0],     st[kkb * 2][nq][1]);
        u32 a1 = cvt_pk_bf16(st[kkb * 2][nq][2],     st[kkb * 2][nq][3]);
        u32 b0 = cvt_pk_bf16(st[kkb * 2 + 1][nq][0], st[kkb * 2 + 1][nq][1]);
        u32 b1 = cvt_pk_bf16(st[kkb * 2 + 1][nq][2], st[kkb * 2 + 1][nq][3]);
        asm("v_permlane32_swap_b32 %0, %1" : "+v"(a0), "+v"(b0));
        asm("v_permlane16_swap_b32 %0, %1" : "+v"(a0), "+v"(b0));
        asm("v_permlane32_swap_b32 %0, %1" : "+v"(a1), "+v"(b1));
        asm("v_permlane16_swap_b32 %0, %1" : "+v"(a1), "+v"(b1));
        union { u32 u[4]; bf16x8 v; } pk_;
        pk_.u[0] = a0; pk_.u[1] = a1; pk_.u[2] = b0; pk_.u[3] = b1;
        ap[nq][kkb] = pk_.v;
      }
    }

    // PV: X(32q x 64d) += P(32x64) @ V^T-tile (vf registers, shared across nq)
#pragma unroll
    for (int kkb = 0; kkb < 2; ++kkb)
#pragma unroll
      for (int ni = 0; ni < 4; ++ni)
#pragma unroll
        for (int nq = 0; nq < 2; ++nq)
          x[nq][ni] = __builtin_amdgcn_mfma_f32_16x16x32_bf16(ap[nq][kkb], vf[kkb][ni],
                                                              x[nq][ni], 0, 0, 0);

    // counted wait: tile kt+1's 4 loads landed; kt+2's 4 stay in flight across barrier
    if (kt < 30) {
      asm volatile("s_waitcnt vmcnt(4)" ::: "memory");
      __builtin_amdgcn_s_barrier();
    } else if (kt == 30) {
      asm volatile("s_waitcnt vmcnt(0)" ::: "memory");
      __builtin_amdgcn_s_barrier();
    }
  }

  // finalize: one-time cross-g row-sum reduce, divide, write merged-head bf16
#pragma unroll
  for (int nq = 0; nq < 2; ++nq) {
    float lt = l_run[nq] + __shfl_xor(l_run[nq], 16);
    lt += __shfl_xor(lt, 32);
    float li = 1.0f / lt;
#pragma unroll
    for (int j = 0; j < 4; ++j) {
      float lv = __shfl(li, g * 4 + j);
      int srw = b * 2048 + qblk * 128 + wv * 32 + nq * 16 + g * 4 + j;
#pragma unroll
      for (int ni = 0; ni < 4; ++ni) {
        int col = h * 64 + ni * 16 + q16;
        Xb[(size_t)srw * 1024 + col] = f2bf(x[nq][ni][j] * lv);
      }
    }
  }
#undef STAGE
}

// ---------------- host launch ----------------
extern "C" void kernel_launch(void* const* d_in, const int* in_sizes, int n_in,
                              void* d_out, int out_size, void* d_ws, size_t ws_size,
                              hipStream_t stream) {
  (void)in_sizes; (void)n_in; (void)out_size; (void)ws_size;
  const float* q  = (const float*)d_in[0];
  const float* k  = (const float*)d_in[1];
  const float* v  = (const float*)d_in[2];
  const float* Wq = (const float*)d_in[3];
  const float* bq = (const float*)d_in[4];
  const float* Wk = (const float*)d_in[5];
  const float* bk = (const float*)d_in[6];
  const float* Wv = (const float*)d_in[7];
  const float* bv = (const float*)d_in[8];
  const float* Wo = (const float*)d_in[9];
  const float* bo = (const float*)d_in[10];

  char* W = (char*)d_ws;
  const size_t MB = 1ull << 20;
  u16* qbf = (u16*)(W + 0 * MB);    // [4096][1024] bf16
  u16* kbf = (u16*)(W + 8 * MB);
  u16* vbf = (u16*)(W + 16 * MB);
  u16* wqt = (u16*)(W + 24 * MB);   // [1024][1024] bf16 (transposed)
  u16* wkt = (u16*)(W + 26 * MB);
  u16* wvt = (u16*)(W + 28 * MB);
  u16* wot = (u16*)(W + 30 * MB);
  u16* Qh  = (u16*)(W + 32 * MB);   // [32][2048][64] bf16 (pre-scaled)
  u16* Kh  = (u16*)(W + 40 * MB);
  u16* Vtb = (u16*)(W + 56 * MB);   // [32][64][2048] (written directly by gemm_qkv)
  u16* Xb  = (u16*)(W + 64 * MB);   // [4096][1024] bf16

  convert_in<<<2048, 256, 0, stream>>>(q, k, v, qbf, kbf, vbf);
  convert_w<<<dim3(16, 16, 4), 256, 0, stream>>>(Wq, Wk, Wv, Wo, wqt, wkt, wvt, wot);
  const float QSCALE = 0.125f * 1.4426950408889634f;  // fold 1/sqrt(dk) * log2(e) into Q
  gemm_qkv<<<dim3(8, 32, 3), 256, 0, stream>>>(qbf, kbf, vbf, wqt, wkt, wvt,
                                               bq, bk, bv, Qh, Kh, Vtb, QSCALE);
  attn_kernel<<<dim3(16, 32), 256, 0, stream>>>(Qh, Kh, Vtb, Xb);
  gemm_out<<<dim3(8, 32), 256, 0, stream>>>(Xb, wot, bo, (float*)d_out);
}